// Round 3
// baseline (209.351 us; speedup 1.0000x reference)
//
#include <hip/hip_runtime.h>
#include <cstddef>

#define BB 4
#define HH 8
#define SS 2048
// Q pre-scale: (1/sqrt(8)) * log2(e)  -> scores come out of MFMA already in exp2 space
#define QSC 0.5101336573f
// mask pre-scale: -10000 * log2(e)
#define MSC (-14426.950408889634f)

typedef __attribute__((ext_vector_type(4))) float v4f;
typedef __attribute__((ext_vector_type(8))) _Float16 v8h;
typedef __attribute__((ext_vector_type(4))) _Float16 v4h;

// ---------------- Kernel 1: q/k projection (f16) + x transpose (f16) ----------------
// One thread per (bh,s) row. Writes: Qh[bh][s][8] f16 (q pre-scaled by QSC),
// Kh[bh][s][8] f16, XT[bh][d][s] f16, and (block 0) a 2048-entry ones row.
__global__ __launch_bounds__(256) void proj_kernel(
    const float* __restrict__ x, const float* __restrict__ Wq,
    const float* __restrict__ bq, const float* __restrict__ Wk,
    const float* __restrict__ bk, _Float16* __restrict__ Qh,
    _Float16* __restrict__ Kh, _Float16* __restrict__ XT,
    _Float16* __restrict__ ones_row) {
  __shared__ _Float16 xt[8 * 264];  // [d][s-in-block], pitch 264 keeps b128 reads aligned
  const int tid = threadIdx.x;
  const int t = blockIdx.x * 256 + tid;     // global row
  const int bh = blockIdx.x >> 3;           // 8 blocks per bh
  const int sb = (blockIdx.x & 7) * 256;
  if (blockIdx.x == 0) {  // fill ones row for the PV l-column
    v8h one;
#pragma unroll
    for (int i = 0; i < 8; ++i) one[i] = (_Float16)1.0f;
    *(v8h*)(ones_row + tid * 8) = one;
  }
  const float4 x0 = ((const float4*)(x + (size_t)t * 8))[0];
  const float4 x1 = ((const float4*)(x + (size_t)t * 8))[1];
  const float xr[8] = {x0.x, x0.y, x0.z, x0.w, x1.x, x1.y, x1.z, x1.w};
  v8h qv, kv;
#pragma unroll
  for (int i = 0; i < 8; ++i) {
    float aq = bq[i], ak = bk[i];
#pragma unroll
    for (int j = 0; j < 8; ++j) {
      aq = fmaf(xr[j], Wq[i * 8 + j], aq);
      ak = fmaf(xr[j], Wk[i * 8 + j], ak);
    }
    qv[i] = (_Float16)(aq * QSC);
    kv[i] = (_Float16)ak;
  }
  *(v8h*)(Qh + (size_t)t * 8) = qv;
  *(v8h*)(Kh + (size_t)t * 8) = kv;
#pragma unroll
  for (int d = 0; d < 8; ++d) xt[d * 264 + tid] = (_Float16)xr[d];
  __syncthreads();
  const int d = tid >> 5, k8 = (tid & 31) * 8;
  *(v8h*)(XT + ((size_t)bh * 8 + d) * SS + sb + k8) =
      *(const v8h*)(xt + d * 264 + k8);
}

// ---------------- Kernel 2: barrier-free MFMA attention ----------------
// grid (128, 4): blockIdx.y = b, blockIdx.x = 16-row q tile. 512 thr = 8 waves;
// wave w = head w (8 heads share the same mask tile via L1/L2).
// No online softmax: shift[q] = min_k(mask)*MSC + 8 (computed in prologue) bounds
// the true score max to within ~25 exp2-units -> single-pass additive softmax.
// QK^T as S^T via mfma_f32_16x16x32_f16 with C = -shift; mask folded by one fma
// (dwordx4 loads straight from the ORIGINAL mask layout: the 4 r's of the C-frag
// are contiguous in k). PV: S^T C-frag IS the A-operand; B-column 8 = ones -> l
// comes out of the MFMA accumulator for free.
__global__ __launch_bounds__(512, 4) void attn_kernel(
    const float* __restrict__ mask, const _Float16* __restrict__ Qh,
    const _Float16* __restrict__ Kh, const _Float16* __restrict__ XT,
    const _Float16* __restrict__ ones_row, float* __restrict__ out) {
  __shared__ float sred[16][33];
  __shared__ float shiftL[16];
  const int b = blockIdx.y;
  const int qb = blockIdx.x * 16;
  const int tid = threadIdx.x;
  const int wave = tid >> 6, lane = tid & 63;
  const int bh = b * HH + wave;
  const int quad = lane >> 4, q15 = lane & 15;

  // ---- prologue: shift[q] = min_k mask[b][qb+q][k] * MSC + 8 (coalesced scan)
  {
    const int q = tid >> 5, seg = tid & 31;
    const float4* row = (const float4*)(mask + ((size_t)b * SS + qb + q) * SS);
    float mn = 3.0e38f;
#pragma unroll
    for (int i = 0; i < 16; ++i) {
      const float4 v = row[seg + i * 32];
      mn = fminf(mn, fminf(fminf(v.x, v.y), fminf(v.z, v.w)));
    }
    sred[q][seg] = mn;
  }
  __syncthreads();
  if (tid < 16) {
    float mn = sred[tid][0];
#pragma unroll
    for (int s = 1; s < 32; ++s) mn = fminf(mn, sred[tid][s]);
    shiftL[tid] = fmaf(mn, MSC, 8.0f);  // MSC<0: min(mask)*MSC = max over k
  }
  __syncthreads();
  const float nshift = -shiftL[q15];
  const v4f cinit = {nshift, nshift, nshift, nshift};

  v8h qfrag;  // B-operand: Q[q=lane&15][k], real only in quad 0 (k=0..7)
  {
    const v8h ql = *(const v8h*)(Qh + ((size_t)bh * SS + qb + q15) * 8);
#pragma unroll
    for (int i = 0; i < 8; ++i) qfrag[i] = (quad == 0) ? ql[i] : (_Float16)0;
  }
  // per-lane pointers (set once; zero per-chunk select cost)
  const _Float16* xbase =
      (q15 < 8) ? (XT + ((size_t)bh * 8 + q15) * SS) : ones_row;
  const float* mbase = mask + ((size_t)b * SS + qb + q15) * SS;
  const _Float16* kbase = Kh + ((size_t)bh * SS + q15) * 8;

  v4f o = {0.f, 0.f, 0.f, 0.f};
  for (int kb = 0; kb < SS; kb += 64) {
    v4f c[4];
#pragma unroll
    for (int t = 0; t < 4; ++t)
      c[t] = __builtin_amdgcn_mfma_f32_16x16x32_f16(
          *(const v8h*)(kbase + (size_t)(kb + t * 16) * 8), qfrag, cinit, 0, 0,
          0);
    v4h pa[4];
#pragma unroll
    for (int t = 0; t < 4; ++t) {
      const v4f mv = *(const v4f*)(mbase + kb + t * 16 + quad * 4);
#pragma unroll
      for (int r = 0; r < 4; ++r)
        pa[t][r] =
            (_Float16)__builtin_amdgcn_exp2f(fmaf(mv[r], MSC, c[t][r]));
    }
#pragma unroll
    for (int t = 0; t < 4; ++t)
      o = __builtin_amdgcn_mfma_f32_16x16x16f16(
          pa[t], *(const v4h*)(xbase + kb + t * 16 + quad * 4), o, 0, 0, 0);
  }

  // epilogue: l = D[q][8] lives at lane quad*16+8, reg r; broadcast + normalize
#pragma unroll
  for (int r = 0; r < 4; ++r) {
    const float lr = __shfl(o[r], quad * 16 + 8);
    if (q15 < 8) {
      out[((size_t)bh * SS + qb + quad * 4 + r) * 8 + q15] = o[r] / lr;
    }
  }
}

extern "C" void kernel_launch(void* const* d_in, const int* in_sizes, int n_in,
                              void* d_out, int out_size, void* d_ws, size_t ws_size,
                              hipStream_t stream) {
  (void)in_sizes;
  (void)n_in;
  (void)out_size;
  (void)ws_size;
  const float* x = (const float*)d_in[0];
  const float* mask = (const float*)d_in[1];
  const float* Wq = (const float*)d_in[2];
  const float* bq = (const float*)d_in[3];
  const float* Wk = (const float*)d_in[4];
  const float* bk = (const float*)d_in[5];
  _Float16* Qh = (_Float16*)d_ws;                      // 1 MB
  _Float16* Kh = Qh + (size_t)BB * HH * SS * 8;        // 1 MB
  _Float16* XT = Kh + (size_t)BB * HH * SS * 8;        // 1 MB
  _Float16* ones_row = XT + (size_t)BB * HH * SS * 8;  // 4 KB
  float* out = (float*)d_out;

  proj_kernel<<<dim3(BB * HH * SS / 256), dim3(256), 0, stream>>>(
      x, Wq, bq, Wk, bk, Qh, Kh, XT, ones_row);
  attn_kernel<<<dim3(SS / 16, BB), dim3(512), 0, stream>>>(
      mask, Qh, Kh, XT, ones_row, out);
}